// Round 8
// baseline (223.577 us; speedup 1.0000x reference)
//
#include <hip/hip_runtime.h>

#define NBOX    25200
#define NQ4     6300           // NBOX/4
#define NBATCH  16
#define NCLS    80
#define MAXDET  100
#define NBUCKET 1024
#define CAP     13824          // expected candidates ~12600, +15 sigma
#define SCORE_THR 0.5f
#define IOU_THR   0.5f
#define NGROUP  16             // 64 buckets per group
#define PREP_REP 4             // AMPLIFICATION PROBE: prep+epilogue x4 (idempotent);
                               // dur = base + 3*(T_prep+T_epi). Revert next round.

// Exact replication of reference fp32 arithmetic: no FMA contraction.
__device__ __forceinline__ void mk_corners(float x, float y, float w, float h,
                                           float& x1, float& y1, float& x2, float& y2) {
#pragma clang fp contract(off)
    float hw = w * 0.5f;
    float hh = h * 0.5f;
    x1 = x - hw; y1 = y - hh; x2 = x + hw; y2 = y + hh;
}

__device__ __forceinline__ float areaf(float x1, float y1, float x2, float y2) {
#pragma clang fp contract(off)
    return (x2 - x1) * (y2 - y1);
}

// Division-free suppression test (see round 7): (inter+inter) > denom matches
// fl(inter/denom) > 0.5 outside a ~1.5e-8 half-ulp band; denom chain bit-identical.
__device__ __forceinline__ bool iou_gt(float kx1, float ky1, float kx2, float ky2, float ka,
                                       float cx1, float cy1, float cx2, float cy2, float ca) {
#pragma clang fp contract(off)
    float lx = fmaxf(kx1, cx1);
    float ly = fmaxf(ky1, cy1);
    float rx = fminf(kx2, cx2);
    float ry = fminf(ky2, cy2);
    float w  = fmaxf(rx - lx, 0.0f);
    float h  = fmaxf(ry - ly, 0.0f);
    float inter = w * h;
    float denom = ka + ca - inter + 1e-9f;   // same rounding chain as reference
    return (inter + inter) > denom;          // == inter/denom > 0.5 in exact reals
}

__device__ __forceinline__ float readlane_f(float v, int j) {
    return __uint_as_float((unsigned)__builtin_amdgcn_readlane((int)__float_as_uint(v), j));
}

__device__ __forceinline__ unsigned score_key(float s) {
    // score in [0.5, 1): ekey in [0, 2^23); bkt = top 10 bits, el = low 13
    return __float_as_uint(s) - 0x3F000000u;
}

__global__ __launch_bounds__(1024)
void nms_kernel(const float* __restrict__ boxes_xywh,
                const float* __restrict__ objectness,
                const float* __restrict__ class_prob,
                float* __restrict__ out) {
    __shared__ unsigned s_hist[NBUCKET];
    __shared__ unsigned s_start[NBUCKET];
    __shared__ unsigned s_a[CAP];          // scattered (bucketed, unsorted-in-bucket)
    __shared__ unsigned s_b[CAP];          // sorted descending (filled lazily, group-pipelined)
    __shared__ float4   s_kbox[MAXDET];
    __shared__ float    s_karea[MAXDET];   // cached kept-box areas
    __shared__ unsigned s_kept_idx[MAXDET];
    __shared__ unsigned s_wsum[16];
    __shared__ unsigned s_woff[16];
    __shared__ int      s_count;

    const int b = blockIdx.x;
    const int t = threadIdx.x;
    const int w = t >> 6;
    const int l = t & 63;
    const float* obj = objectness + (size_t)b * NBOX;
    const float* bx  = boxes_xywh + (size_t)b * NBOX * 4;

    // per-bucket rank sort (one wave per call)
    auto sort_bucket = [&](int bkt) {
        unsigned h = s_hist[bkt];
        if (h == 0u) return;
        unsigned end = s_start[bkt];        // post-scatter: sum_{j>=bkt} h[j]
        unsigned hi  = (end > CAP) ? CAP : end;
        unsigned lo  = (end >= h) ? end - h : 0u;
        if (lo > hi) lo = hi;
        unsigned sz = hi - lo;
        if (sz == 0u) return;
        if (sz <= 64u) {
            unsigned v = (l < (int)sz) ? s_a[lo + (unsigned)l] : 0u;
            int rank = 0;
            for (unsigned j = 0; j < sz; ++j)
                rank += ((unsigned)__shfl((int)v, (int)j) > v) ? 1 : 0;
            if (l < (int)sz) s_b[lo + (unsigned)rank] = v;
        } else {
            for (unsigned bb = 0; bb < sz; bb += 64u) {
                bool valid = bb + (unsigned)l < sz;
                unsigned v = valid ? s_a[lo + bb + (unsigned)l] : 0u;
                int rank = 0;
                for (unsigned j = 0; j < sz; ++j)
                    rank += (s_a[lo + j] > v) ? 1 : 0;
                if (valid) s_b[lo + (unsigned)rank] = v;
            }
        }
    };

    float4 r[7];

    // ==== AMPLIFICATION: phases 0-3 + group-0 pre-sort repeated PREP_REP
    // times. Idempotent: scan recomputes s_start from s_hist each rep;
    // scatter re-fills s_a (in-bucket order may permute across reps, but
    // keys are unique so the rank sorts produce identical s_b). ====
    for (int rep = 0; rep < PREP_REP; ++rep) {
        // ---- Phase 0: register-cache all objectness (7 float4 per thread) ----
        // memory clobber between reps prevents load-dedup across reps
        __asm__ volatile("" ::: "memory");
#pragma unroll
        for (int i = 0; i < 7; ++i) {
            int n4 = t + (i << 10);
            if (n4 < NQ4) r[i] = *(const float4*)(obj + n4 * 4);
        }

        // ---- Phase 1: histogram over top-10 mantissa bits ----
        s_hist[t] = 0u;
        __syncthreads();
#pragma unroll
        for (int i = 0; i < 7; ++i) {
            int n4 = t + (i << 10);
            if (n4 < NQ4) {
                float sv[4] = {r[i].x, r[i].y, r[i].z, r[i].w};
#pragma unroll
                for (int u = 0; u < 4; ++u) {
                    if (sv[u] >= SCORE_THR) {
                        unsigned bkt = score_key(sv[u]) >> 13;
                        if (bkt > 1023u) bkt = 1023u;
                        atomicAdd(&s_hist[bkt], 1u);
                    }
                }
            }
        }
        __syncthreads();

        // ---- Phase 2: reverse exclusive scan via wave scans ----
        {
            unsigned f = s_hist[1023 - t];
            unsigned v = f;
#pragma unroll
            for (int off = 1; off < 64; off <<= 1) {
                unsigned u = (unsigned)__shfl_up((int)v, off);
                if (l >= off) v += u;
            }
            if (l == 63) s_wsum[w] = v;
            __syncthreads();
            if (t < 64) {
                unsigned x = (t < 16) ? s_wsum[t] : 0u;
                unsigned y = x;
#pragma unroll
                for (int off = 1; off < 16; off <<= 1) {
                    unsigned u = (unsigned)__shfl_up((int)y, off);
                    if (t >= off) y += u;
                }
                if (t < 16) s_woff[t] = y - x;
            }
            __syncthreads();
            s_start[1023 - t] = v - f + s_woff[w];
        }
        __syncthreads();

        // ---- Phase 3: EAGER scatter of ALL candidates ----
#pragma unroll
        for (int i = 0; i < 7; ++i) {
            int n4 = t + (i << 10);
            if (n4 < NQ4) {
                float sv[4] = {r[i].x, r[i].y, r[i].z, r[i].w};
#pragma unroll
                for (int u = 0; u < 4; ++u) {
                    if (sv[u] >= SCORE_THR) {
                        unsigned ekey = score_key(sv[u]);
                        unsigned bkt  = ekey >> 13;
                        if (bkt > 1023u) bkt = 1023u;
                        int n = n4 * 4 + u;
                        unsigned pos = atomicAdd(&s_start[bkt], 1u);
                        if (pos < CAP)
                            s_a[pos] = ((ekey & 0x1FFFu) << 18) | (0x3FFFFu - (unsigned)n);
                    }
                }
            }
        }
        __syncthreads();

        // ---- pre-sort group 0 (top 64 buckets) with all 16 waves ----
        for (int bkt = (1023 - 63) + w; bkt <= 1023; bkt += 16) sort_bucket(bkt);
        __syncthreads();
    }

    if (t == 0) s_count = 0;
    __syncthreads();

    // ---- Pipelined group loop: wave 0 greedy on g; waves 1-15 sort g+1 ----
    int count = 0;
    for (int g = 0; g < NGROUP; ++g) {
        const int BH = 1023 - (g << 6);
        const int BL = BH - 63;

        if (w == 0) {
            unsigned glo = (g == 0) ? 0u : s_start[BH + 1];
            unsigned ghi = s_start[BL];
            if (glo > CAP) glo = CAP;
            if (ghi > CAP) ghi = CAP;

            if (glo < ghi && count < MAXDET) {
                // depth-4 software pipeline for box gathers (manual reg rotation)
                unsigned i0, i1, i2, i3;
                float4 q0, q1, q2, q3;
                auto loadc = [&](unsigned cb, unsigned& ix, float4& q) {
                    ix = 0u; q = make_float4(0.f, 0.f, 0.f, 0.f);
                    unsigned p0 = cb + (unsigned)l;
                    if (p0 < ghi) {
                        unsigned p = s_b[p0];
                        ix = 0x3FFFFu - (p & 0x3FFFFu);
                        q = *(const float4*)(bx + (size_t)ix * 4);
                    }
                };
                loadc(glo,        i0, q0);
                loadc(glo + 64u,  i1, q1);
                loadc(glo + 128u, i2, q2);
                loadc(glo + 192u, i3, q3);

                for (unsigned base = glo; base < ghi && count < MAXDET; base += 64u) {
                    unsigned cidx = i0; float4 cq = q0;
                    i0 = i1; q0 = q1;
                    i1 = i2; q1 = q2;
                    i2 = i3; q2 = q3;
                    loadc(base + 256u, i3, q3);

                    int m = (int)(ghi - base); if (m > 64) m = 64;
                    float cx1, cy1, cx2, cy2;
                    mk_corners(cq.x, cq.y, cq.z, cq.w, cx1, cy1, cx2, cy2);
                    float ca = areaf(cx1, cy1, cx2, cy2);

                    // vs-kept pre-filter: batches of 4 independent LDS loads;
                    // wave-uniform early exit every 16 kept
                    bool sup = (l >= m);
                    int k = 0;
                    for (; k + 4 <= count; k += 4) {
                        float4 kb0 = s_kbox[k],     kb1 = s_kbox[k + 1];
                        float4 kb2 = s_kbox[k + 2], kb3 = s_kbox[k + 3];
                        float ka0 = s_karea[k],     ka1 = s_karea[k + 1];
                        float ka2 = s_karea[k + 2], ka3 = s_karea[k + 3];
                        sup = sup | iou_gt(kb0.x, kb0.y, kb0.z, kb0.w, ka0,
                                           cx1, cy1, cx2, cy2, ca);
                        sup = sup | iou_gt(kb1.x, kb1.y, kb1.z, kb1.w, ka1,
                                           cx1, cy1, cx2, cy2, ca);
                        sup = sup | iou_gt(kb2.x, kb2.y, kb2.z, kb2.w, ka2,
                                           cx1, cy1, cx2, cy2, ca);
                        sup = sup | iou_gt(kb3.x, kb3.y, kb3.z, kb3.w, ka3,
                                           cx1, cy1, cx2, cy2, ca);
                        if (((k & 12) == 12) && __all(sup)) { k = count; break; }
                    }
                    for (; k < count; ++k) {
                        float4 kb = s_kbox[k];
                        sup = sup | iou_gt(kb.x, kb.y, kb.z, kb.w, s_karea[k],
                                           cx1, cy1, cx2, cy2, ca);
                    }
                    unsigned long long act = __ballot(!sup);

                    // serial accept loop: v_readlane broadcasts, writes deferred
                    unsigned long long accmask = 0ull;
                    const int cbase = count;
                    while (act != 0ull && count < MAXDET) {
                        int j = (int)__builtin_ctzll(act);
                        accmask |= 1ull << j;
                        float bx1 = readlane_f(cx1, j), by1 = readlane_f(cy1, j);
                        float bx2 = readlane_f(cx2, j), by2 = readlane_f(cy2, j);
                        float bar = readlane_f(ca, j);
                        bool su = iou_gt(bx1, by1, bx2, by2, bar, cx1, cy1, cx2, cy2, ca);
                        ++count;
                        act &= ~(1ull << j);
                        act &= ~__ballot(su);
                    }

                    // parallel deferred writeback; score gathered only on accept
                    if (accmask & (1ull << l)) {
                        int slot = cbase + (int)__popcll(accmask & ((1ull << l) - 1ull));
                        s_kbox[slot] = make_float4(cx1, cy1, cx2, cy2);
                        s_karea[slot] = ca;
                        s_kept_idx[slot] = cidx;
                        float* ob = out + ((size_t)b * MAXDET + slot) * 4;
                        ob[0] = cx1; ob[1] = cy1; ob[2] = cx2; ob[3] = cy2;
                        out[NBATCH * MAXDET * 4 + b * MAXDET + slot] = obj[cidx];
                    }
                    __asm__ volatile("s_waitcnt lgkmcnt(0)" ::: "memory");
                }
            }
            if (l == 0) s_count = count;
        } else if (g + 1 < NGROUP) {
            // waves 1-15: sort next group's 64 buckets (all already scattered)
            const int BH2 = BH - 64, BL2 = BH2 - 63;
            for (int bkt = BL2 + (w - 1); bkt <= BH2; bkt += 15) sort_bucket(bkt);
        }
        __syncthreads();
        if (s_count >= MAXDET) break;
    }

    // ==== AMPLIFICATION: epilogue repeated PREP_REP times (idempotent —
    // rewrites identical values; barrier between reps blocks store-merging) ====
    const int cf = s_count;
    for (int rep = 0; rep < PREP_REP; ++rep) {
        for (int e = t; e < MAXDET * 4; e += 1024) {
            if ((e >> 2) >= cf) out[(size_t)b * MAXDET * 4 + e] = 0.0f;
        }
        for (int i = t; i < MAXDET; i += 1024) {
            if (i >= cf) out[NBATCH * MAXDET * 4 + b * MAXDET + i] = 0.0f;
        }
        const float* cp = class_prob + (size_t)b * NBOX * NCLS;
        float* oc = out + NBATCH * MAXDET * 5 + (size_t)b * MAXDET * NCLS;
        float4* oc4 = (float4*)oc;
        const int NQC = NCLS / 4;          // 20 float4 per class row (320 B, 16B-aligned)
        const int nq = cf * NQC;
        for (int e4 = t; e4 < nq; e4 += 1024) {
            int i  = e4 / NQC;
            int c4 = e4 - i * NQC;
            oc4[e4] = *((const float4*)(cp + (size_t)s_kept_idx[i] * NCLS) + c4);
        }
        for (int e4 = t + nq; e4 < MAXDET * NQC; e4 += 1024)
            oc4[e4] = make_float4(0.0f, 0.0f, 0.0f, 0.0f);
        if (t == 0)
            out[NBATCH * MAXDET * 5 + NBATCH * MAXDET * NCLS + b] = (float)cf;
        __syncthreads();
        __asm__ volatile("" ::: "memory");
    }
}

extern "C" void kernel_launch(void* const* d_in, const int* in_sizes, int n_in,
                              void* d_out, int out_size, void* d_ws, size_t ws_size,
                              hipStream_t stream) {
    const float* boxes = (const float*)d_in[0];
    const float* objn  = (const float*)d_in[1];
    const float* clsp  = (const float*)d_in[2];
    float* out = (float*)d_out;
    nms_kernel<<<dim3(NBATCH), dim3(1024), 0, stream>>>(boxes, objn, clsp, out);
}

// Round 9
// 190.735 us; speedup vs baseline: 1.1722x; 1.1722x over previous
//
#include <hip/hip_runtime.h>

#define NBOX    25200
#define NQ4     6300           // NBOX/4
#define NBATCH  16
#define NCLS    80
#define MAXDET  100
#define NBUCKET 1024
#define CAP     13824          // expected candidates ~12600, +15 sigma
#define SCORE_THR 0.5f
#define IOU_THR   0.5f
#define NGROUP  16             // 64 buckets per group
#define MAXCH   24             // chunks per group eligible for helper masks

// Exact replication of reference fp32 arithmetic: no FMA contraction.
__device__ __forceinline__ void mk_corners(float x, float y, float w, float h,
                                           float& x1, float& y1, float& x2, float& y2) {
#pragma clang fp contract(off)
    float hw = w * 0.5f;
    float hh = h * 0.5f;
    x1 = x - hw; y1 = y - hh; x2 = x + hw; y2 = y + hh;
}

__device__ __forceinline__ float areaf(float x1, float y1, float x2, float y2) {
#pragma clang fp contract(off)
    return (x2 - x1) * (y2 - y1);
}

// Division-free suppression test (round 7, verified): (inter+inter) > denom
// matches fl(inter/denom) > 0.5 outside a ~1.5e-8 half-ulp band; denom
// rounding chain bit-identical to reference.
__device__ __forceinline__ bool iou_gt(float kx1, float ky1, float kx2, float ky2, float ka,
                                       float cx1, float cy1, float cx2, float cy2, float ca) {
#pragma clang fp contract(off)
    float lx = fmaxf(kx1, cx1);
    float ly = fmaxf(ky1, cy1);
    float rx = fminf(kx2, cx2);
    float ry = fminf(ry = fminf(ky2, cy2), ry);  // placeholder removed below
    return false;
}

// (real definition — the above stub is unused; see iou_gt2)
__device__ __forceinline__ bool iou_gt2(float kx1, float ky1, float kx2, float ky2, float ka,
                                        float cx1, float cy1, float cx2, float cy2, float ca) {
#pragma clang fp contract(off)
    float lx = fmaxf(kx1, cx1);
    float ly = fmaxf(ky1, cy1);
    float rx = fminf(kx2, cx2);
    float ry = fminf(ky2, cy2);
    float w  = fmaxf(rx - lx, 0.0f);
    float h  = fmaxf(ry - ly, 0.0f);
    float inter = w * h;
    float denom = ka + ca - inter + 1e-9f;   // same rounding chain as reference
    return (inter + inter) > denom;          // == inter/denom > 0.5 in exact reals
}
#define iou_gt iou_gt2

__device__ __forceinline__ float readlane_f(float v, int j) {
    return __uint_as_float((unsigned)__builtin_amdgcn_readlane((int)__float_as_uint(v), j));
}

__device__ __forceinline__ unsigned score_key(float s) {
    // score in [0.5, 1): ekey in [0, 2^23); bkt = top 10 bits, el = low 13
    return __float_as_uint(s) - 0x3F000000u;
}

__global__ __launch_bounds__(1024)
void nms_kernel(const float* __restrict__ boxes_xywh,
                const float* __restrict__ objectness,
                const float* __restrict__ class_prob,
                float* __restrict__ out) {
    __shared__ unsigned s_hist[NBUCKET];
    __shared__ unsigned s_start[NBUCKET];
    __shared__ unsigned s_a[CAP];          // scattered (bucketed, unsorted-in-bucket)
    __shared__ unsigned s_b[CAP];          // sorted descending (filled lazily, group-pipelined)
    __shared__ float4   s_kbox[MAXDET];
    __shared__ float    s_karea[MAXDET];   // cached kept-box areas
    __shared__ unsigned s_kept_idx[MAXDET];
    __shared__ unsigned s_wsum[16];
    __shared__ unsigned s_woff[16];
    __shared__ int      s_count;
    // chunk-pipeline handshake (all cross-wave deps barrier-separated)
    __shared__ unsigned s_mlo[MAXCH], s_mhi[MAXCH];  // helper mask halves (atomicOr-merged)
    __shared__ unsigned s_wm[MAXCH];                 // kept-prefix covered by mask
    __shared__ int      s_cnt2[2];                   // double-buffered count snapshots

    const int b = blockIdx.x;
    const int t = threadIdx.x;
    const int w = t >> 6;
    const int l = t & 63;
    const float* obj = objectness + (size_t)b * NBOX;
    const float* bx  = boxes_xywh + (size_t)b * NBOX * 4;

    // ---- Phase 0: register-cache all objectness (7 float4 per thread) ----
    float4 r[7];
#pragma unroll
    for (int i = 0; i < 7; ++i) {
        int n4 = t + (i << 10);
        if (n4 < NQ4) r[i] = *(const float4*)(obj + n4 * 4);
    }

    // ---- Phase 1: histogram over top-10 mantissa bits ----
    s_hist[t] = 0u;
    __syncthreads();
#pragma unroll
    for (int i = 0; i < 7; ++i) {
        int n4 = t + (i << 10);
        if (n4 < NQ4) {
            float sv[4] = {r[i].x, r[i].y, r[i].z, r[i].w};
#pragma unroll
            for (int u = 0; u < 4; ++u) {
                if (sv[u] >= SCORE_THR) {
                    unsigned bkt = score_key(sv[u]) >> 13;
                    if (bkt > 1023u) bkt = 1023u;
                    atomicAdd(&s_hist[bkt], 1u);
                }
            }
        }
    }
    __syncthreads();

    // ---- Phase 2: reverse exclusive scan via wave scans ----
    {
        unsigned f = s_hist[1023 - t];
        unsigned v = f;
#pragma unroll
        for (int off = 1; off < 64; off <<= 1) {
            unsigned u = (unsigned)__shfl_up((int)v, off);
            if (l >= off) v += u;
        }
        if (l == 63) s_wsum[w] = v;
        __syncthreads();
        if (t < 64) {
            unsigned x = (t < 16) ? s_wsum[t] : 0u;
            unsigned y = x;
#pragma unroll
            for (int off = 1; off < 16; off <<= 1) {
                unsigned u = (unsigned)__shfl_up((int)y, off);
                if (t >= off) y += u;
            }
            if (t < 16) s_woff[t] = y - x;
        }
        __syncthreads();
        s_start[1023 - t] = v - f + s_woff[w];
    }
    if (t == 0) s_count = 0;
    __syncthreads();

    // ---- Phase 3: EAGER scatter of ALL candidates ----
#pragma unroll
    for (int i = 0; i < 7; ++i) {
        int n4 = t + (i << 10);
        if (n4 < NQ4) {
            float sv[4] = {r[i].x, r[i].y, r[i].z, r[i].w};
#pragma unroll
            for (int u = 0; u < 4; ++u) {
                if (sv[u] >= SCORE_THR) {
                    unsigned ekey = score_key(sv[u]);
                    unsigned bkt  = ekey >> 13;
                    if (bkt > 1023u) bkt = 1023u;
                    int n = n4 * 4 + u;
                    unsigned pos = atomicAdd(&s_start[bkt], 1u);
                    if (pos < CAP)
                        s_a[pos] = ((ekey & 0x1FFFu) << 18) | (0x3FFFFu - (unsigned)n);
                }
            }
        }
    }
    __syncthreads();

    // per-bucket rank sort (one wave per call)
    auto sort_bucket = [&](int bkt) {
        unsigned h = s_hist[bkt];
        if (h == 0u) return;
        unsigned end = s_start[bkt];
        unsigned hi  = (end > CAP) ? CAP : end;
        unsigned lo  = (end >= h) ? end - h : 0u;
        if (lo > hi) lo = hi;
        unsigned sz = hi - lo;
        if (sz == 0u) return;
        if (sz <= 64u) {
            unsigned v = (l < (int)sz) ? s_a[lo + (unsigned)l] : 0u;
            int rank = 0;
            for (unsigned j = 0; j < sz; ++j)
                rank += ((unsigned)__shfl((int)v, (int)j) > v) ? 1 : 0;
            if (l < (int)sz) s_b[lo + (unsigned)rank] = v;
        } else {
            for (unsigned bb = 0; bb < sz; bb += 64u) {
                bool valid = bb + (unsigned)l < sz;
                unsigned v = valid ? s_a[lo + bb + (unsigned)l] : 0u;
                int rank = 0;
                for (unsigned j = 0; j < sz; ++j)
                    rank += (s_a[lo + j] > v) ? 1 : 0;
                if (valid) s_b[lo + (unsigned)rank] = v;
            }
        }
    };

    // ---- pre-sort group 0 (top 64 buckets) with all 16 waves ----
    for (int bkt = (1023 - 63) + w; bkt <= 1023; bkt += 16) sort_bucket(bkt);
    __syncthreads();

    // ---- Group loop with chunk-pipelined roles:
    //      wave 0: greedy chunk i | waves 1-7: mask chunk i+1 | waves 8-15: sort g+1 ----
    int count = 0;
    for (int g = 0; g < NGROUP; ++g) {
        const int BH = 1023 - (g << 6);
        const int BL = BH - 63;
        unsigned glo = (g == 0) ? 0u : s_start[BH + 1];
        unsigned ghi = s_start[BL];
        if (glo > CAP) glo = CAP;
        if (ghi > CAP) ghi = CAP;
        int nch = (ghi > glo) ? (int)((ghi - glo + 63u) >> 6) : 0;

        if (t < MAXCH) { s_mlo[t] = 0u; s_mhi[t] = 0u; s_wm[t] = 0u; }
        if (t == 0) { s_cnt2[0] = s_count; s_cnt2[1] = s_count; }
        __syncthreads();

        // wave-0 depth-4 gather pipeline
        unsigned i0 = 0, i1 = 0, i2 = 0, i3 = 0;
        float4 q0, q1, q2, q3;
        auto loadc = [&](unsigned cb, unsigned& ix, float4& q) {
            ix = 0u; q = make_float4(0.f, 0.f, 0.f, 0.f);
            unsigned p0 = cb + (unsigned)l;
            if (p0 < ghi) {
                unsigned p = s_b[p0];
                ix = 0x3FFFFu - (p & 0x3FFFFu);
                q = *(const float4*)(bx + (size_t)ix * 4);
            }
        };
        if (w == 0 && nch > 0 && count < MAXDET) {
            loadc(glo,        i0, q0);
            loadc(glo + 64u,  i1, q1);
            loadc(glo + 128u, i2, q2);
            loadc(glo + 192u, i3, q3);
        }

        bool broke = false;
        int sorted_i = 0;
        const int BL2 = BH - 127;   // group g+1 lowest bucket
        for (int i = 0; i < nch; ++i) {
            const int cprev = s_cnt2[(i + 1) & 1];   // count after chunk i-1 (barrier-ordered)
            if (cprev >= MAXDET) { broke = true; break; }   // uniform

            if (w == 0) {
                if (count < MAXDET) {
                    unsigned base = glo + ((unsigned)i << 6);
                    unsigned cidx = i0; float4 cq = q0;
                    i0 = i1; q0 = q1;
                    i1 = i2; q1 = q2;
                    i2 = i3; q2 = q3;
                    loadc(base + 256u, i3, q3);

                    int m = (int)(ghi - base); if (m > 64) m = 64;
                    float cx1, cy1, cx2, cy2;
                    mk_corners(cq.x, cq.y, cq.z, cq.w, cx1, cy1, cx2, cy2);
                    float ca = areaf(cx1, cy1, cx2, cy2);

                    // helper mask (covers kept [0..wm)) + delta [wm..count)
                    int wm = 0; unsigned mlo = 0u, mhi = 0u;
                    if (i < MAXCH) { wm = (int)s_wm[i]; mlo = s_mlo[i]; mhi = s_mhi[i]; }
                    unsigned long long hm = ((unsigned long long)mhi << 32) | mlo;
                    bool sup = (l >= m) | (((hm >> l) & 1ull) != 0ull);
                    int k = wm;
                    for (; k + 4 <= count; k += 4) {
                        float4 kb0 = s_kbox[k],     kb1 = s_kbox[k + 1];
                        float4 kb2 = s_kbox[k + 2], kb3 = s_kbox[k + 3];
                        float ka0 = s_karea[k],     ka1 = s_karea[k + 1];
                        float ka2 = s_karea[k + 2], ka3 = s_karea[k + 3];
                        sup = sup | iou_gt(kb0.x, kb0.y, kb0.z, kb0.w, ka0,
                                           cx1, cy1, cx2, cy2, ca);
                        sup = sup | iou_gt(kb1.x, kb1.y, kb1.z, kb1.w, ka1,
                                           cx1, cy1, cx2, cy2, ca);
                        sup = sup | iou_gt(kb2.x, kb2.y, kb2.z, kb2.w, ka2,
                                           cx1, cy1, cx2, cy2, ca);
                        sup = sup | iou_gt(kb3.x, kb3.y, kb3.z, kb3.w, ka3,
                                           cx1, cy1, cx2, cy2, ca);
                        if (((k & 12) == 12) && __all(sup)) { k = count; break; }
                    }
                    for (; k < count; ++k) {
                        float4 kb = s_kbox[k];
                        sup = sup | iou_gt(kb.x, kb.y, kb.z, kb.w, s_karea[k],
                                           cx1, cy1, cx2, cy2, ca);
                    }
                    unsigned long long act = __ballot(!sup);

                    // serial accept loop (unchanged)
                    unsigned long long accmask = 0ull;
                    const int cbase = count;
                    while (act != 0ull && count < MAXDET) {
                        int j = (int)__builtin_ctzll(act);
                        accmask |= 1ull << j;
                        float bx1 = readlane_f(cx1, j), by1 = readlane_f(cy1, j);
                        float bx2 = readlane_f(cx2, j), by2 = readlane_f(cy2, j);
                        float bar = readlane_f(ca, j);
                        bool su = iou_gt(bx1, by1, bx2, by2, bar, cx1, cy1, cx2, cy2, ca);
                        ++count;
                        act &= ~(1ull << j);
                        act &= ~__ballot(su);
                    }

                    if (accmask & (1ull << l)) {
                        int slot = cbase + (int)__popcll(accmask & ((1ull << l) - 1ull));
                        s_kbox[slot] = make_float4(cx1, cy1, cx2, cy2);
                        s_karea[slot] = ca;
                        s_kept_idx[slot] = cidx;
                        float* ob = out + ((size_t)b * MAXDET + slot) * 4;
                        ob[0] = cx1; ob[1] = cy1; ob[2] = cx2; ob[3] = cy2;
                        out[NBATCH * MAXDET * 4 + b * MAXDET + slot] = obj[cidx];
                    }
                    __asm__ volatile("s_waitcnt lgkmcnt(0)" ::: "memory");
                }
                if (l == 0) s_cnt2[i & 1] = count;   // snapshot for iteration i+1
            } else if (w <= 7) {
                // waves 1-7: mask chunk i+1 vs kept [0..cprev), 7-way kept-slice
                int ci = i + 1;
                if (ci < nch && ci < MAXCH) {
                    unsigned p0 = glo + ((unsigned)ci << 6) + (unsigned)l;
                    bool valid = p0 < ghi;
                    float4 qq = make_float4(0.f, 0.f, 0.f, 0.f);
                    if (valid) {
                        unsigned p = s_b[p0];
                        unsigned ix = 0x3FFFFu - (p & 0x3FFFFu);
                        qq = *(const float4*)(bx + (size_t)ix * 4);
                    }
                    float hx1, hy1, hx2, hy2;
                    mk_corners(qq.x, qq.y, qq.z, qq.w, hx1, hy1, hx2, hy2);
                    float hca = areaf(hx1, hy1, hx2, hy2);
                    int k0 = (w - 1) * cprev / 7;
                    int k1 = w * cprev / 7;
                    bool sup = !valid;
                    for (int k = k0; k < k1; ++k) {
                        float4 kb = s_kbox[k];
                        sup = sup | iou_gt(kb.x, kb.y, kb.z, kb.w, s_karea[k],
                                           hx1, hy1, hx2, hy2, hca);
                    }
                    unsigned long long bm = __ballot(sup);
                    if (l == 0) {
                        unsigned lo32 = (unsigned)bm, hi32 = (unsigned)(bm >> 32);
                        if (lo32) atomicOr(&s_mlo[ci], lo32);
                        if (hi32) atomicOr(&s_mhi[ci], hi32);
                        if (w == 1) s_wm[ci] = (unsigned)cprev;
                    }
                }
            } else {
                // waves 8-15: sort group g+1, one owned bucket per iteration
                if (g + 1 < NGROUP && sorted_i < 8) {
                    sort_bucket(BL2 + (w - 8) * 8 + sorted_i);
                    ++sorted_i;
                }
            }
            __syncthreads();
        }
        // finish any next-group sorts not covered by loop iterations
        if (!broke && g + 1 < NGROUP && w >= 8) {
            for (; sorted_i < 8; ++sorted_i)
                sort_bucket(BL2 + (w - 8) * 8 + sorted_i);
        }
        if (w == 0 && l == 0) s_count = count;
        __syncthreads();
        if (s_count >= MAXDET) break;
    }

    // ---- Epilogue: gather class rows (float4-vectorized), zero tails, count ----
    const int cf = s_count;
    for (int e = t; e < MAXDET * 4; e += 1024) {
        if ((e >> 2) >= cf) out[(size_t)b * MAXDET * 4 + e] = 0.0f;
    }
    for (int i = t; i < MAXDET; i += 1024) {
        if (i >= cf) out[NBATCH * MAXDET * 4 + b * MAXDET + i] = 0.0f;
    }
    const float* cp = class_prob + (size_t)b * NBOX * NCLS;
    float* oc = out + NBATCH * MAXDET * 5 + (size_t)b * MAXDET * NCLS;
    float4* oc4 = (float4*)oc;
    const int NQC = NCLS / 4;              // 20 float4 per class row (320 B, 16B-aligned)
    const int nq = cf * NQC;
    for (int e4 = t; e4 < nq; e4 += 1024) {
        int i  = e4 / NQC;
        int c4 = e4 - i * NQC;
        oc4[e4] = *((const float4*)(cp + (size_t)s_kept_idx[i] * NCLS) + c4);
    }
    for (int e4 = t + nq; e4 < MAXDET * NQC; e4 += 1024)
        oc4[e4] = make_float4(0.0f, 0.0f, 0.0f, 0.0f);
    if (t == 0)
        out[NBATCH * MAXDET * 5 + NBATCH * MAXDET * NCLS + b] = (float)cf;
}

extern "C" void kernel_launch(void* const* d_in, const int* in_sizes, int n_in,
                              void* d_out, int out_size, void* d_ws, size_t ws_size,
                              hipStream_t stream) {
    const float* boxes = (const float*)d_in[0];
    const float* objn  = (const float*)d_in[1];
    const float* clsp  = (const float*)d_in[2];
    float* out = (float*)d_out;
    nms_kernel<<<dim3(NBATCH), dim3(1024), 0, stream>>>(boxes, objn, clsp, out);
}